// Round 6
// baseline (240.889 us; speedup 1.0000x reference)
//
#include <hip/hip_runtime.h>
#include <hip/hip_bf16.h>

// Problem constants
constexpr int Bc = 32, Sc = 4096, Dc = 64, Pc = 8, STRIDEc = 4, Hc = 512;
constexpr int Tc = (Sc - Pc) / STRIDEc + 1;   // 1023
constexpr int Kc = Pc * Dc;                   // 512
constexpr float EPSc = 1e-6f;

typedef __bf16 bf16x8 __attribute__((ext_vector_type(8)));
typedef unsigned short ushort8 __attribute__((ext_vector_type(8)));
typedef float f32x4 __attribute__((ext_vector_type(4)));
typedef unsigned int uint4v __attribute__((ext_vector_type(4)));

__device__ __forceinline__ int n_tok_of(int len) {
    return (len >= Pc) ? ((len - Pc) / STRIDEc + 1) : 1;
}

// fp32 -> bf16 round-to-nearest-even
__device__ __forceinline__ unsigned short f2bf(float f) {
    unsigned u = __builtin_bit_cast(unsigned, f);
    u = (u + 0x7FFFu + ((u >> 16) & 1u)) >> 16;
    return (unsigned short)u;
}
// pack two fp32 -> one uint holding (bf16(lo) | bf16(hi)<<16)
__device__ __forceinline__ unsigned pk2bf(float lo, float hi) {
    return (unsigned)f2bf(lo) | ((unsigned)f2bf(hi) << 16);
}

// ---------------------------------------------------------------------------
// Kernel T: tokens output (pure streaming; also warms x into L2/L3).
// One float4 per thread. No interaction with the GEMM.
// ---------------------------------------------------------------------------
__global__ __launch_bounds__(256) void tokens_kernel(
        const float* __restrict__ x, const int* __restrict__ lengths,
        float* __restrict__ out_tokens) {
    const int idx = blockIdx.x * 256 + threadIdx.x;
    const int row = idx >> 7;          // B*T rows
    const int c4  = idx & 127;         // 128 float4 per row
    const int b = row / Tc;
    const int t = row - b * Tc;
    const int len = lengths[b];
    const int ntok = n_tok_of(len);
    const int p = c4 >> 4;
    const int pos = t * STRIDEc + p;

    float4 v = make_float4(0.f, 0.f, 0.f, 0.f);
    if (t < ntok && pos < len)
        v = *(const float4*)(x + (size_t)b * Sc * Dc + (size_t)t * (STRIDEc * Dc) + c4 * 4);
    *(float4*)(out_tokens + (size_t)row * Kc + c4 * 4) = v;
}

// ---------------------------------------------------------------------------
// Prep: emit W as bf16 in MFMA A-fragment order:
//   elem(n = w*128+ct*16+l15, k = step*32+quad*8+j) at
//   Wfrag[ (((step*4+w)*8+ct)*64 + quad*16 + l15)*8 + j ].
// Also writes token_lengths.
// ---------------------------------------------------------------------------
__global__ __launch_bounds__(256) void prep_kernel(
        const float* __restrict__ W, const int* __restrict__ lengths,
        unsigned short* __restrict__ Wfrag, float* __restrict__ out_tl) {
    __shared__ float tile[32][33];
    const int k0 = blockIdx.x * 32, n0 = blockIdx.y * 32;
    const int r = threadIdx.x >> 3, c = (threadIdx.x & 7) * 4;
    const float4 v = *(const float4*)(W + (size_t)(k0 + r) * Hc + n0 + c);
    tile[c + 0][r] = v.x;
    tile[c + 1][r] = v.y;
    tile[c + 2][r] = v.z;
    tile[c + 3][r] = v.w;
    __syncthreads();
    ushort4 o;
    o.x = f2bf(tile[r][c + 0]);
    o.y = f2bf(tile[r][c + 1]);
    o.z = f2bf(tile[r][c + 2]);
    o.w = f2bf(tile[r][c + 3]);
    const int n   = n0 + r;
    const int kk  = k0 + c;
    const int wv  = n >> 7;
    const int ct  = (n >> 4) & 7;
    const int l15 = n & 15;
    const int stp = kk >> 5;
    const int qd  = (kk >> 3) & 3;
    const size_t off =
        ((((size_t)stp * 4 + wv) * 8 + ct) * 64 + qd * 16 + l15) * 8 + (kk & 7);
    *(ushort4*)(Wfrag + off) = o;
    if (blockIdx.x == 0 && blockIdx.y == 0 && threadIdx.x < Bc)
        out_tl[threadIdx.x] = (float)n_tok_of(lengths[threadIdx.x]);
}

// ---------------------------------------------------------------------------
// Kernel G: bf16-MFMA GEMM (BM=32 x BN=512) + bias + RMSNorm*scale.
// Store-free, barrier-free K-loop: aW fragments direct from L2-hot Wfrag;
// x-fragments ping-pong prefetched one step ahead; packed-bf16 convert in reg.
// Operand-swapped MFMA (D^T): l15 = token row, quad*4+reg = 4 consecutive
// h-cols -> float4 stores in epilogue only.
// ---------------------------------------------------------------------------
__global__ __launch_bounds__(256, 3) void gemm_rms_kernel(
        const float* __restrict__ x, const int* __restrict__ lengths,
        const unsigned short* __restrict__ Wfrag, const float* __restrict__ bias,
        const float* __restrict__ scale, float* __restrict__ hidden) {
    const int b  = blockIdx.y;
    const int t0 = blockIdx.x * 32;
    const int len = lengths[b];
    const int ntok = n_tok_of(len);

    __shared__ float ssbuf[4][32];

    const int tid  = threadIdx.x;
    const int w    = tid >> 6;
    const int lane = tid & 63;
    const int l15  = lane & 15;
    const int quad = lane >> 4;

    f32x4 acc[2][8];                             // [ttile][ctile]
#pragma unroll
    for (int tt = 0; tt < 2; ++tt)
#pragma unroll
        for (int ct = 0; ct < 8; ++ct) acc[tt][ct] = (f32x4){0.f, 0.f, 0.f, 0.f};

    const float* xb = x + (size_t)b * (Sc * Dc);
    const int ft[2] = {t0 + l15, t0 + 16 + l15};

    const unsigned short* wf = Wfrag + ((size_t)w * 8) * 512 + (size_t)lane * 8;

    // x-fragment ping-pong buffers: [buf][tt][half]
    float4 xf[2][2][2];

#define LOAD_X(buf, stp)                                                     \
    {                                                                        \
        const int kf = (stp) * 32 + quad * 8;                                \
        const int pf = kf >> 6;                                              \
        _Pragma("unroll")                                                    \
        for (int tt = 0; tt < 2; ++tt) {                                     \
            const int t = ft[tt];                                            \
            float4 f0 = make_float4(0.f, 0.f, 0.f, 0.f);                     \
            float4 f1 = make_float4(0.f, 0.f, 0.f, 0.f);                     \
            if (t < ntok && (t * STRIDEc + pf) < len) {                      \
                const float* src = xb + (size_t)t * (STRIDEc * Dc) + kf;     \
                f0 = *(const float4*)(src);                                  \
                f1 = *(const float4*)(src + 4);                              \
            }                                                                \
            xf[buf][tt][0] = f0;                                             \
            xf[buf][tt][1] = f1;                                             \
        }                                                                    \
    }

    LOAD_X(0, 0)

    for (int step = 0; step < 16; ++step) {
        const int cur = step & 1;

        // aW fragment loads for this step (L2-hot, coalesced 1KB/instr)
        ushort8 aW[8];
        const unsigned short* wfs = wf + (size_t)step * (4 * 8 * 512);
#pragma unroll
        for (int ct = 0; ct < 8; ++ct)
            aW[ct] = *(const ushort8*)(wfs + ct * 512);

        // prefetch next step's x fragments (independent of this step's MFMA)
        if (step < 15) LOAD_X(cur ^ 1, step + 1)

        // convert current x fragments to bf16
        bf16x8 btok[2];
#pragma unroll
        for (int tt = 0; tt < 2; ++tt) {
            const float4 f0 = xf[cur][tt][0];
            const float4 f1 = xf[cur][tt][1];
            uint4v uu;
            uu[0] = pk2bf(f0.x, f0.y);
            uu[1] = pk2bf(f0.z, f0.w);
            uu[2] = pk2bf(f1.x, f1.y);
            uu[3] = pk2bf(f1.z, f1.w);
            btok[tt] = __builtin_bit_cast(bf16x8, uu);
        }

        // MFMA (operand-swapped)
#pragma unroll
        for (int ct = 0; ct < 8; ++ct) {
            const bf16x8 av = __builtin_bit_cast(bf16x8, aW[ct]);
#pragma unroll
            for (int tt = 0; tt < 2; ++tt)
                acc[tt][ct] = __builtin_amdgcn_mfma_f32_16x16x32_bf16(
                    av, btok[tt], acc[tt][ct], 0, 0, 0);
        }
    }
#undef LOAD_X

    // ---- epilogue: bias, in-register row sums, RMS, scale, float4 stores ----
    float ss[2] = {0.f, 0.f};
#pragma unroll
    for (int ct = 0; ct < 8; ++ct) {
        const f32x4 b4 = *(const f32x4*)(bias + w * 128 + ct * 16 + quad * 4);
#pragma unroll
        for (int tt = 0; tt < 2; ++tt) {
            f32x4 h = acc[tt][ct] + b4;
            acc[tt][ct] = h;
            ss[tt] += h[0] * h[0] + h[1] * h[1] + h[2] * h[2] + h[3] * h[3];
        }
    }
#pragma unroll
    for (int tt = 0; tt < 2; ++tt) {
        float s = ss[tt];
        s += __shfl_xor(s, 16);
        s += __shfl_xor(s, 32);
        if (quad == 0) ssbuf[w][tt * 16 + l15] = s;
    }
    __syncthreads();
    float rstd[2];
#pragma unroll
    for (int tt = 0; tt < 2; ++tt) {
        const int r = tt * 16 + l15;
        const float tot = ssbuf[0][r] + ssbuf[1][r] + ssbuf[2][r] + ssbuf[3][r];
        rstd[tt] = rsqrtf(tot * (1.0f / (float)Hc) + EPSc);
    }
#pragma unroll
    for (int ct = 0; ct < 8; ++ct) {
        const f32x4 s4 = *(const f32x4*)(scale + w * 128 + ct * 16 + quad * 4);
#pragma unroll
        for (int tt = 0; tt < 2; ++tt) {
            const int t = ft[tt];
            if (t < Tc) {
                f32x4 o = acc[tt][ct] * rstd[tt] * s4;
                *(f32x4*)(hidden + ((size_t)b * Tc + t) * Hc
                          + w * 128 + ct * 16 + quad * 4) = o;
            }
        }
    }
}

extern "C" void kernel_launch(void* const* d_in, const int* in_sizes, int n_in,
                              void* d_out, int out_size, void* d_ws, size_t ws_size,
                              hipStream_t stream) {
    const float* x       = (const float*)d_in[0];
    const int*   lengths = (const int*)d_in[1];
    const float* W       = (const float*)d_in[2];
    const float* bias    = (const float*)d_in[3];
    const float* scale   = (const float*)d_in[4];

    const size_t BTH = (size_t)Bc * Tc * Hc;   // 16,760,832
    float* out    = (float*)d_out;
    float* hidden = out;                        // output 0
    float* tl     = out + BTH;                  // output 1 (32 floats)
    float* tokens = out + BTH + Bc;             // output 2

    unsigned short* Wfrag = (unsigned short*)d_ws; // 512x512 bf16, fragment-ordered

    {   // tokens copy (streams x -> L3 warm for the GEMM)
        const int total = Bc * Tc * 128;        // float4 count
        tokens_kernel<<<total / 256, 256, 0, stream>>>(x, lengths, tokens);
    }
    {   // W -> Wfrag (transpose + bf16 + fragment order) and token_lengths
        dim3 grid(Hc / 32, Hc / 32);            // (16,16)
        prep_kernel<<<grid, 256, 0, stream>>>(W, lengths, Wfrag, tl);
    }
    {   // GEMM + RMSNorm, store-free barrier-free K-loop
        dim3 grid(32, Bc);                      // 32 m-blocks x 32 batches
        gemm_rms_kernel<<<grid, 256, 0, stream>>>(x, lengths, Wfrag, bias, scale,
                                                  hidden);
    }
}

// Round 7
// 214.572 us; speedup vs baseline: 1.1226x; 1.1226x over previous
//
#include <hip/hip_runtime.h>
#include <hip/hip_bf16.h>

// Problem constants
constexpr int Bc = 32, Sc = 4096, Dc = 64, Pc = 8, STRIDEc = 4, Hc = 512;
constexpr int Tc = (Sc - Pc) / STRIDEc + 1;   // 1023
constexpr int Kc = Pc * Dc;                   // 512
constexpr float EPSc = 1e-6f;
constexpr int APITCH = 40;                    // A-tile LDS pitch (80B: 2-way = free)

typedef __bf16 bf16x8 __attribute__((ext_vector_type(8)));
typedef unsigned short ushort8 __attribute__((ext_vector_type(8)));
typedef float f32x4 __attribute__((ext_vector_type(4)));

__device__ __forceinline__ int n_tok_of(int len) {
    return (len >= Pc) ? ((len - Pc) / STRIDEc + 1) : 1;
}

// fp32 -> bf16 round-to-nearest-even
__device__ __forceinline__ unsigned short f2bf(float f) {
    unsigned u = __builtin_bit_cast(unsigned, f);
    u = (u + 0x7FFFu + ((u >> 16) & 1u)) >> 16;
    return (unsigned short)u;
}
__device__ __forceinline__ unsigned pk2bf(float lo, float hi) {
    return (unsigned)f2bf(lo) | ((unsigned)f2bf(hi) << 16);
}

// async global->LDS, 16B per lane, LDS dest = wave-uniform base + lane*16
#define GLOAD_LDS16(gp, lp)                                                   \
    __builtin_amdgcn_global_load_lds(                                         \
        (const __attribute__((address_space(1))) void*)(gp),                  \
        (__attribute__((address_space(3))) void*)(lp), 16, 0, 0)

// ---------------------------------------------------------------------------
// Prep: emit W (bf16, transposed) in the GEMM's B-LDS linear order with XOR
// k-group swizzle:
//   Wfrag[ st*16384 + n*32 + slot*8 + j ] = bf16( W[ st*32 + kg*8 + j ][ n ] )
//   where slot = kg ^ ((n>>1)&3).
// So each step's 32KB block DMA-copies verbatim into LDS, and fragment
// ds_read_b128 at (n, kg) -> addr n*64B + (kg^((n>>1)&3))*16B is 2-way
// bank-aliased only (free). Also writes token_lengths.
// ---------------------------------------------------------------------------
__global__ __launch_bounds__(256) void prep_kernel(
        const float* __restrict__ W, const int* __restrict__ lengths,
        unsigned short* __restrict__ Wfrag, float* __restrict__ out_tl) {
    __shared__ float tile[32][33];
    const int k0 = blockIdx.x * 32, n0 = blockIdx.y * 32;
    const int r = threadIdx.x >> 3, c = (threadIdx.x & 7) * 4;
    const float4 v = *(const float4*)(W + (size_t)(k0 + r) * Hc + n0 + c);
    tile[c + 0][r] = v.x;
    tile[c + 1][r] = v.y;
    tile[c + 2][r] = v.z;
    tile[c + 3][r] = v.w;
    __syncthreads();
    ushort4 o;
    o.x = f2bf(tile[r][c + 0]);
    o.y = f2bf(tile[r][c + 1]);
    o.z = f2bf(tile[r][c + 2]);
    o.w = f2bf(tile[r][c + 3]);
    const int n   = n0 + r;
    const int kk  = k0 + c;          // 4 consecutive k, within one 8-group
    const int st  = kk >> 5;
    const int kg  = (kk >> 3) & 3;
    const int j   = kk & 7;          // 0 or 4
    const int slot = kg ^ ((n >> 1) & 3);
    const size_t off = (size_t)st * 16384 + (size_t)n * 32 + slot * 8 + j;
    *(ushort4*)(Wfrag + off) = o;
    if (blockIdx.x == 0 && blockIdx.y == 0 && threadIdx.x < Bc)
        out_tl[threadIdx.x] = (float)n_tok_of(lengths[threadIdx.x]);
}

// ---------------------------------------------------------------------------
// Fused: tokens-write + bf16-MFMA GEMM (BM=64 x BN=512, BK=32) + bias +
// RMSNorm*scale. Classic 2-barrier K-loop:
//   barrier; stage A (masked x -> tokens store + bf16 ds_write, pitch 40)
//   + stage B (8x global_load_lds dwordx4, swizzled-contiguous); barrier;
//   ds_read_b128 frags; 32 MFMA/wave.
// Operand-swapped MFMA (D^T): l15 = token row, quad*4+reg = 4 consecutive
// h-cols -> float4 epilogue stores, in-register RMS partial sums.
// ---------------------------------------------------------------------------
__global__ __launch_bounds__(256) void fused_kernel(
        const float* __restrict__ x, const int* __restrict__ lengths,
        const unsigned short* __restrict__ Wfrag, const float* __restrict__ bias,
        const float* __restrict__ scale, float* __restrict__ hidden,
        float* __restrict__ tokens) {
    const int b  = blockIdx.y;
    const int t0 = blockIdx.x * 64;
    const int len = lengths[b];
    const int ntok = n_tok_of(len);

    __shared__ unsigned short As[64 * APITCH];   // A tile, bf16, pitch 40
    __shared__ unsigned short Bs[512 * 32];      // B tile, bf16, swizzled linear
    __shared__ float ssbuf[4][64];

    const int tid  = threadIdx.x;
    const int w    = tid >> 6;
    const int lane = tid & 63;
    const int l15  = lane & 15;
    const int quad = lane >> 4;

    f32x4 acc[4][8];
#pragma unroll
    for (int tt = 0; tt < 4; ++tt)
#pragma unroll
        for (int ct = 0; ct < 8; ++ct) acc[tt][ct] = (f32x4){0.f, 0.f, 0.f, 0.f};

    const float* xb   = x + (size_t)b * (Sc * Dc);
    float*       tokb = tokens + (size_t)b * Tc * Kc;

    // loop-invariant fragment read pointers
    const unsigned short* a_rd[4];
#pragma unroll
    for (int tt = 0; tt < 4; ++tt)
        a_rd[tt] = As + (tt * 16 + l15) * APITCH + quad * 8;
    const unsigned short* b_rd[8];
#pragma unroll
    for (int ct = 0; ct < 8; ++ct) {
        const int n = w * 128 + ct * 16 + l15;
        b_rd[ct] = Bs + n * 32 + (quad ^ ((n >> 1) & 3)) * 8;
    }

    for (int step = 0; step < 16; ++step) {
        const int k0 = step * 32;
        if (step) __syncthreads();               // prev step's frag reads done

        // ---- stage A: masked x load -> tokens store + bf16 ds_write ----
#pragma unroll
        for (int it = 0; it < 2; ++it) {
            const int l = tid + it * 256;
            const int r = l >> 3;                // 0..63
            const int c = (l & 7) * 4;           // 0..28 (ushort offset)
            const int t = t0 + r;
            const int kk = k0 + c;
            const int pos = t * STRIDEc + (kk >> 6);
            float4 v = make_float4(0.f, 0.f, 0.f, 0.f);
            if (t < ntok && pos < len)
                v = *(const float4*)(xb + (size_t)t * (STRIDEc * Dc) + kk);
            if (t < Tc)
                *(float4*)(tokb + (size_t)t * Kc + kk) = v;
            ushort4 h4;
            h4.x = f2bf(v.x); h4.y = f2bf(v.y); h4.z = f2bf(v.z); h4.w = f2bf(v.w);
            *(ushort4*)(As + r * APITCH + c) = h4;
        }

        // ---- stage B: 32KB swizzled step-block, async DMA to LDS ----
        const unsigned short* wstep = Wfrag + (size_t)step * 16384;
#pragma unroll
        for (int it = 0; it < 8; ++it) {
            const int cc = w * 8 + it;           // 1KB chunk id (wave-uniform)
            GLOAD_LDS16(wstep + (size_t)cc * 512 + lane * 8, Bs + cc * 512);
        }
        __syncthreads();                          // drains vmcnt (DMA) + lgkm

        // ---- fragments + MFMA ----
        bf16x8 btok[4];
#pragma unroll
        for (int tt = 0; tt < 4; ++tt)
            btok[tt] = __builtin_bit_cast(bf16x8, *(const ushort8*)a_rd[tt]);
#pragma unroll
        for (int ct = 0; ct < 8; ++ct) {
            const bf16x8 av = __builtin_bit_cast(bf16x8, *(const ushort8*)b_rd[ct]);
#pragma unroll
            for (int tt = 0; tt < 4; ++tt)
                acc[tt][ct] = __builtin_amdgcn_mfma_f32_16x16x32_bf16(
                    av, btok[tt], acc[tt][ct], 0, 0, 0);
        }
    }

    // ---- epilogue: bias, in-register row sums, RMS, scale, float4 stores ----
    float ss[4] = {0.f, 0.f, 0.f, 0.f};
#pragma unroll
    for (int ct = 0; ct < 8; ++ct) {
        const f32x4 b4 = *(const f32x4*)(bias + w * 128 + ct * 16 + quad * 4);
#pragma unroll
        for (int tt = 0; tt < 4; ++tt) {
            f32x4 h = acc[tt][ct] + b4;
            acc[tt][ct] = h;
            ss[tt] += h[0] * h[0] + h[1] * h[1] + h[2] * h[2] + h[3] * h[3];
        }
    }
#pragma unroll
    for (int tt = 0; tt < 4; ++tt) {
        float s = ss[tt];
        s += __shfl_xor(s, 16);
        s += __shfl_xor(s, 32);
        if (quad == 0) ssbuf[w][tt * 16 + l15] = s;
    }
    __syncthreads();
    float rstd[4];
#pragma unroll
    for (int tt = 0; tt < 4; ++tt) {
        const int r = tt * 16 + l15;
        const float tot = ssbuf[0][r] + ssbuf[1][r] + ssbuf[2][r] + ssbuf[3][r];
        rstd[tt] = rsqrtf(tot * (1.0f / (float)Hc) + EPSc);
    }
#pragma unroll
    for (int ct = 0; ct < 8; ++ct) {
        const f32x4 s4 = *(const f32x4*)(scale + w * 128 + ct * 16 + quad * 4);
#pragma unroll
        for (int tt = 0; tt < 4; ++tt) {
            const int t = t0 + tt * 16 + l15;
            if (t < Tc) {
                f32x4 o = acc[tt][ct] * rstd[tt] * s4;
                *(f32x4*)(hidden + ((size_t)b * Tc + t) * Hc
                          + w * 128 + ct * 16 + quad * 4) = o;
            }
        }
    }
}

extern "C" void kernel_launch(void* const* d_in, const int* in_sizes, int n_in,
                              void* d_out, int out_size, void* d_ws, size_t ws_size,
                              hipStream_t stream) {
    const float* x       = (const float*)d_in[0];
    const int*   lengths = (const int*)d_in[1];
    const float* W       = (const float*)d_in[2];
    const float* bias    = (const float*)d_in[3];
    const float* scale   = (const float*)d_in[4];

    const size_t BTH = (size_t)Bc * Tc * Hc;   // 16,760,832
    float* out    = (float*)d_out;
    float* hidden = out;                        // output 0
    float* tl     = out + BTH;                  // output 1 (32 floats)
    float* tokens = out + BTH + Bc;             // output 2

    unsigned short* Wfrag = (unsigned short*)d_ws; // 512 KB, swizzled LDS order

    {   // W -> Wfrag (transpose + bf16 + swizzled linear order) and token_lengths
        dim3 grid(Hc / 32, Hc / 32);            // (16,16)
        prep_kernel<<<grid, 256, 0, stream>>>(W, lengths, Wfrag, tl);
    }
    {   // fused tokens + GEMM + RMSNorm (2-barrier K-loop, DMA B-staging)
        dim3 grid(16, Bc);                      // 16 m-blocks x 32 batches
        fused_kernel<<<grid, 256, 0, stream>>>(x, lengths, Wfrag, bias, scale,
                                               hidden, tokens);
    }
}

// Round 8
// 199.972 us; speedup vs baseline: 1.2046x; 1.0730x over previous
//
#include <hip/hip_runtime.h>
#include <hip/hip_bf16.h>

// Problem constants
constexpr int Bc = 32, Sc = 4096, Dc = 64, Pc = 8, STRIDEc = 4, Hc = 512;
constexpr int Tc = (Sc - Pc) / STRIDEc + 1;   // 1023
constexpr int Kc = Pc * Dc;                   // 512
constexpr float EPSc = 1e-6f;
constexpr int APITCH = 40;                    // A-tile LDS pitch (80B: 2-way = free)

typedef __bf16 bf16x8 __attribute__((ext_vector_type(8)));
typedef unsigned short ushort8 __attribute__((ext_vector_type(8)));
typedef float f32x4 __attribute__((ext_vector_type(4)));

__device__ __forceinline__ int n_tok_of(int len) {
    return (len >= Pc) ? ((len - Pc) / STRIDEc + 1) : 1;
}

// fp32 -> bf16 round-to-nearest-even
__device__ __forceinline__ unsigned short f2bf(float f) {
    unsigned u = __builtin_bit_cast(unsigned, f);
    u = (u + 0x7FFFu + ((u >> 16) & 1u)) >> 16;
    return (unsigned short)u;
}

// ---------------------------------------------------------------------------
// Prep: emit W (bf16, transposed) in the GEMM's B-LDS linear order with XOR
// k-group swizzle (verified in R7):
//   Wfrag[ st*16384 + n*32 + slot*8 + j ] = bf16( W[ st*32 + kg*8 + j ][ n ] )
//   slot = kg ^ ((n>>1)&3).
// Each step's 32KB block copies verbatim into LDS; fragment ds_read_b128 at
// (n, kg) is 2-way bank-aliased only (free). Also writes token_lengths.
// ---------------------------------------------------------------------------
__global__ __launch_bounds__(256) void prep_kernel(
        const float* __restrict__ W, const int* __restrict__ lengths,
        unsigned short* __restrict__ Wfrag, float* __restrict__ out_tl) {
    __shared__ float tile[32][33];
    const int k0 = blockIdx.x * 32, n0 = blockIdx.y * 32;
    const int r = threadIdx.x >> 3, c = (threadIdx.x & 7) * 4;
    const float4 v = *(const float4*)(W + (size_t)(k0 + r) * Hc + n0 + c);
    tile[c + 0][r] = v.x;
    tile[c + 1][r] = v.y;
    tile[c + 2][r] = v.z;
    tile[c + 3][r] = v.w;
    __syncthreads();
    ushort4 o;
    o.x = f2bf(tile[r][c + 0]);
    o.y = f2bf(tile[r][c + 1]);
    o.z = f2bf(tile[r][c + 2]);
    o.w = f2bf(tile[r][c + 3]);
    const int n   = n0 + r;
    const int kk  = k0 + c;
    const int st  = kk >> 5;
    const int kg  = (kk >> 3) & 3;
    const int j   = kk & 7;          // 0 or 4
    const int slot = kg ^ ((n >> 1) & 3);
    const size_t off = (size_t)st * 16384 + (size_t)n * 32 + slot * 8 + j;
    *(ushort4*)(Wfrag + off) = o;
    if (blockIdx.x == 0 && blockIdx.y == 0 && threadIdx.x < Bc)
        out_tl[threadIdx.x] = (float)n_tok_of(lengths[threadIdx.x]);
}

// ---------------------------------------------------------------------------
// Fused: tokens-write + bf16-MFMA GEMM (BM=32 x BN=512, BK=32) + bias +
// RMSNorm*scale. R3-style register-prefetch 2-barrier K-loop, BM=32 for
// 1024 blocks (4/CU candidate), 35.5KB LDS, VGPR-capped for 3 waves/SIMD.
//   barrier; commit regs (tokens store + A ds_write pitch40 + B ds_write
//   linear-swizzled); barrier; issue next step's global loads; MFMA.
// Operand-swapped MFMA (D^T): l15 = token row, quad*4+reg = 4 consecutive
// h-cols -> float4 epilogue stores, in-register RMS partial sums.
// ---------------------------------------------------------------------------
__global__ __launch_bounds__(256, 3) void fused_kernel(
        const float* __restrict__ x, const int* __restrict__ lengths,
        const unsigned short* __restrict__ Wfrag, const float* __restrict__ bias,
        const float* __restrict__ scale, float* __restrict__ hidden,
        float* __restrict__ tokens) {
    const int b  = blockIdx.y;
    const int t0 = blockIdx.x * 32;
    const int len = lengths[b];
    const int ntok = n_tok_of(len);

    __shared__ unsigned short As[32 * APITCH];   // 2.5 KB, pitch 40
    __shared__ unsigned short Bs[512 * 32];      // 32 KB, swizzled linear
    __shared__ float ssbuf[4][32];

    const int tid  = threadIdx.x;
    const int w    = tid >> 6;
    const int lane = tid & 63;
    const int l15  = lane & 15;
    const int quad = lane >> 4;

    f32x4 acc[2][8];
#pragma unroll
    for (int tt = 0; tt < 2; ++tt)
#pragma unroll
        for (int ct = 0; ct < 8; ++ct) acc[tt][ct] = (f32x4){0.f, 0.f, 0.f, 0.f};

    const float* xb   = x + (size_t)b * (Sc * Dc);
    float*       tokb = tokens + (size_t)b * Tc * Kc;

    // A staging coords: 1 float4/thread (32 rows x 8 chunks)
    const int a_r = tid >> 3;            // 0..31
    const int a_c = (tid & 7) * 4;       // 0..28
    const int a_t = t0 + a_r;
    const bool a_tv = (a_t < Tc);
    const float* a_src = xb + (size_t)a_t * (STRIDEc * Dc);

    // loop-invariant fragment read pointers
    const unsigned short* a_rd[2];
#pragma unroll
    for (int tt = 0; tt < 2; ++tt)
        a_rd[tt] = As + (tt * 16 + l15) * APITCH + quad * 8;
    const unsigned short* b_rd[8];
#pragma unroll
    for (int ct = 0; ct < 8; ++ct) {
        const int n = w * 128 + ct * 16 + l15;
        b_rd[ct] = Bs + n * 32 + (quad ^ ((n >> 1) & 3)) * 8;
    }

    float4  ra;
    ushort8 rb[8];

    // ---- prologue loads (step 0) ----
    {
        const int pos = a_t * STRIDEc + (a_c >> 6);
        ra = make_float4(0.f, 0.f, 0.f, 0.f);
        if (a_t < ntok && pos < len) ra = *(const float4*)(a_src + a_c);
#pragma unroll
        for (int it = 0; it < 8; ++it)
            rb[it] = *(const ushort8*)(Wfrag + (size_t)(tid + it * 256) * 8);
    }

    for (int step = 0; step < 16; ++step) {
        const int k0 = step * 32;
        if (step) __syncthreads();               // prev step's frag reads done

        // ---- commit staged regs: tokens store + A/B ds_writes ----
        {
            const float4 v = ra;
            if (a_tv)
                *(float4*)(tokb + (size_t)a_t * Kc + k0 + a_c) = v;
            ushort4 h4;
            h4.x = f2bf(v.x); h4.y = f2bf(v.y); h4.z = f2bf(v.z); h4.w = f2bf(v.w);
            *(ushort4*)(As + a_r * APITCH + a_c) = h4;
        }
#pragma unroll
        for (int it = 0; it < 8; ++it)
            *(ushort8*)(Bs + (size_t)(tid + it * 256) * 8) = rb[it];
        __syncthreads();

        // ---- prefetch next step into registers (overlaps MFMA below) ----
        if (step < 15) {
            const int kn = k0 + 32 + a_c;
            const int pos = a_t * STRIDEc + (kn >> 6);
            ra = make_float4(0.f, 0.f, 0.f, 0.f);
            if (a_t < ntok && pos < len) ra = *(const float4*)(a_src + kn);
            const unsigned short* wsrc = Wfrag + (size_t)(step + 1) * 16384;
#pragma unroll
            for (int it = 0; it < 8; ++it)
                rb[it] = *(const ushort8*)(wsrc + (size_t)(tid + it * 256) * 8);
        }

        // ---- fragments + MFMA ----
        bf16x8 btok[2];
#pragma unroll
        for (int tt = 0; tt < 2; ++tt)
            btok[tt] = __builtin_bit_cast(bf16x8, *(const ushort8*)a_rd[tt]);
#pragma unroll
        for (int ct = 0; ct < 8; ++ct) {
            const bf16x8 av = __builtin_bit_cast(bf16x8, *(const ushort8*)b_rd[ct]);
#pragma unroll
            for (int tt = 0; tt < 2; ++tt)
                acc[tt][ct] = __builtin_amdgcn_mfma_f32_16x16x32_bf16(
                    av, btok[tt], acc[tt][ct], 0, 0, 0);
        }
    }

    // ---- epilogue: bias, in-register row sums, RMS, scale, float4 stores ----
    float ss[2] = {0.f, 0.f};
#pragma unroll
    for (int ct = 0; ct < 8; ++ct) {
        const f32x4 b4 = *(const f32x4*)(bias + w * 128 + ct * 16 + quad * 4);
#pragma unroll
        for (int tt = 0; tt < 2; ++tt) {
            f32x4 h = acc[tt][ct] + b4;
            acc[tt][ct] = h;
            ss[tt] += h[0] * h[0] + h[1] * h[1] + h[2] * h[2] + h[3] * h[3];
        }
    }
#pragma unroll
    for (int tt = 0; tt < 2; ++tt) {
        float s = ss[tt];
        s += __shfl_xor(s, 16);
        s += __shfl_xor(s, 32);
        if (quad == 0) ssbuf[w][tt * 16 + l15] = s;
    }
    __syncthreads();
    float rstd[2];
#pragma unroll
    for (int tt = 0; tt < 2; ++tt) {
        const int r = tt * 16 + l15;
        const float tot = ssbuf[0][r] + ssbuf[1][r] + ssbuf[2][r] + ssbuf[3][r];
        rstd[tt] = rsqrtf(tot * (1.0f / (float)Hc) + EPSc);
    }
#pragma unroll
    for (int ct = 0; ct < 8; ++ct) {
        const f32x4 s4 = *(const f32x4*)(scale + w * 128 + ct * 16 + quad * 4);
#pragma unroll
        for (int tt = 0; tt < 2; ++tt) {
            const int t = t0 + tt * 16 + l15;
            if (t < Tc) {
                f32x4 o = acc[tt][ct] * rstd[tt] * s4;
                *(f32x4*)(hidden + ((size_t)b * Tc + t) * Hc
                          + w * 128 + ct * 16 + quad * 4) = o;
            }
        }
    }
}

extern "C" void kernel_launch(void* const* d_in, const int* in_sizes, int n_in,
                              void* d_out, int out_size, void* d_ws, size_t ws_size,
                              hipStream_t stream) {
    const float* x       = (const float*)d_in[0];
    const int*   lengths = (const int*)d_in[1];
    const float* W       = (const float*)d_in[2];
    const float* bias    = (const float*)d_in[3];
    const float* scale   = (const float*)d_in[4];

    const size_t BTH = (size_t)Bc * Tc * Hc;   // 16,760,832
    float* out    = (float*)d_out;
    float* hidden = out;                        // output 0
    float* tl     = out + BTH;                  // output 1 (32 floats)
    float* tokens = out + BTH + Bc;             // output 2

    unsigned short* Wfrag = (unsigned short*)d_ws; // 512 KB, swizzled LDS order

    {   // W -> Wfrag (transpose + bf16 + swizzled linear order) and token_lengths
        dim3 grid(Hc / 32, Hc / 32);            // (16,16)
        prep_kernel<<<grid, 256, 0, stream>>>(W, lengths, Wfrag, tl);
    }
    {   // fused tokens + GEMM + RMSNorm (BM=32, register-prefetch K-loop)
        dim3 grid(32, Bc);                      // 32 m-blocks x 32 batches
        fused_kernel<<<grid, 256, 0, stream>>>(x, lengths, Wfrag, bias, scale,
                                               hidden, tokens);
    }
}